// Round 4
// baseline (428.191 us; speedup 1.0000x reference)
//
#include <hip/hip_runtime.h>
#include <hip/hip_bf16.h>

typedef __bf16 bf16;
typedef bf16 bf16x4 __attribute__((ext_vector_type(4)));
typedef bf16 bf16x8 __attribute__((ext_vector_type(8)));
typedef float f32x4 __attribute__((ext_vector_type(4)));

#define HID 1024
#define NHEADS 16
#define HD 64
#define SEQ 4096

__device__ __forceinline__ void gll16(const void* g, void* l) {
  __builtin_amdgcn_global_load_lds(
      (const __attribute__((address_space(1))) void*)g,
      (__attribute__((address_space(3))) void*)l, 16, 0, 0);
}

// ---------------------------------------------------------------------------
// Prep: z=0 convert X fp32->bf16; z=1..4 transpose+convert W -> Wt[out][in],
// folding attention scale (0.125, exact) into Wq.
// ---------------------------------------------------------------------------
__global__ __launch_bounds__(256)
void prep_kernel(const float* __restrict__ X,
                 const float* __restrict__ Wq, const float* __restrict__ Wk,
                 const float* __restrict__ Wv, const float* __restrict__ Wo,
                 bf16* __restrict__ Xb, bf16* __restrict__ Wt)
{
  const int z = blockIdx.z, t = threadIdx.x, bx = blockIdx.x;
  if (z == 0) {
    const float4* src = (const float4*)X;
    const int gid = bx * 256 + t;
    #pragma unroll
    for (int i = 0; i < 16; ++i) {
      float4 v = src[gid + i * 65536];
      bf16x4 o = {(bf16)v.x, (bf16)v.y, (bf16)v.z, (bf16)v.w};
      *(bf16x4*)&Xb[(size_t)(gid + i * 65536) * 4] = o;
    }
  } else {
    const float* W = (z == 1) ? Wq : (z == 2) ? Wk : (z == 3) ? Wv : Wo;
    bf16* dst = Wt + (size_t)(z - 1) * HID * HID;
    const float scale = (z == 1) ? 0.125f : 1.0f;
    __shared__ bf16 T[64][68];
    const int tr = (bx >> 4) * 64, tc = (bx & 15) * 64;
    #pragma unroll
    for (int p = 0; p < 4; ++p) {
      int row = (t >> 4) + p * 16;
      float4 v = *(const float4*)&W[(size_t)(tr + row) * HID + tc + (t & 15) * 4];
      T[row][(t & 15) * 4 + 0] = (bf16)(v.x * scale);
      T[row][(t & 15) * 4 + 1] = (bf16)(v.y * scale);
      T[row][(t & 15) * 4 + 2] = (bf16)(v.z * scale);
      T[row][(t & 15) * 4 + 3] = (bf16)(v.w * scale);
    }
    __syncthreads();
    #pragma unroll
    for (int p = 0; p < 4; ++p) {
      int rp = (t >> 4) + p * 16;
      int cb = (t & 15) * 4;
      bf16x4 o = {T[cb + 0][rp], T[cb + 1][rp], T[cb + 2][rp], T[cb + 3][rp]};
      *(bf16x4*)&dst[(size_t)(tc + rp) * HID + tr + cb] = o;
    }
  }
}

// ---------------------------------------------------------------------------
// QKV GEMM: C = Xb[M,K] @ Wt[z][N,K]^T. 128x128 tile, BK=64, global_load_lds
// with chunk-rotation swizzle. z=2 writes V transposed (Vt[hid][seq]).
// ---------------------------------------------------------------------------
__global__ __launch_bounds__(256)
void qkv_gemm(const bf16* __restrict__ A, const bf16* __restrict__ Wt,
              bf16* __restrict__ Qg, bf16* __restrict__ Kg,
              bf16* __restrict__ Vt)
{
  __shared__ bf16 sbuf[16384];
  bf16* As = sbuf;
  bf16* Bs = sbuf + 8192;

  const int t = threadIdx.x, lane = t & 63, w = t >> 6;
  const int z = blockIdx.z;
  const int n0 = blockIdx.x * 128, m0 = blockIdx.y * 128;
  const bf16* Bt = Wt + (size_t)z * HID * HID;
  const int wm = (w & 1) * 64, wn = (w >> 1) * 64;
  const int fr = lane & 15, quad = lane >> 4;

  f32x4 acc[4][4] = {};

  const int sr = lane >> 3;
  const int sc = ((lane & 7) - sr) & 7;
  const bf16* ga = A  + (size_t)(m0 + w * 32 + sr) * HID + sc * 8;
  const bf16* gb = Bt + (size_t)(n0 + w * 32 + sr) * HID + sc * 8;

  for (int k0 = 0; k0 < HID; k0 += 64) {
    __syncthreads();
    #pragma unroll
    for (int c = 0; c < 4; ++c) {
      gll16(ga + (size_t)(c * 8) * HID + k0, As + (w * 32 + c * 8) * 64);
      gll16(gb + (size_t)(c * 8) * HID + k0, Bs + (w * 32 + c * 8) * 64);
    }
    __syncthreads();
    #pragma unroll
    for (int ks = 0; ks < 2; ++ks) {
      bf16x8 af[4], bg[4];
      #pragma unroll
      for (int i = 0; i < 4; ++i)
        af[i] = *(const bf16x8*)&As[(wm + i * 16 + fr) * 64 +
                                    ((ks * 4 + quad + fr) & 7) * 8];
      #pragma unroll
      for (int i = 0; i < 4; ++i)
        bg[i] = *(const bf16x8*)&Bs[(wn + i * 16 + fr) * 64 +
                                    ((ks * 4 + quad + fr) & 7) * 8];
      #pragma unroll
      for (int mi = 0; mi < 4; ++mi)
        #pragma unroll
        for (int ni = 0; ni < 4; ++ni)
          acc[mi][ni] = __builtin_amdgcn_mfma_f32_16x16x32_bf16(
              af[mi], bg[ni], acc[mi][ni], 0, 0, 0);
    }
  }

  if (z < 2) {
    bf16* C = z ? Kg : Qg;
    #pragma unroll
    for (int mi = 0; mi < 4; ++mi)
      #pragma unroll
      for (int ni = 0; ni < 4; ++ni)
        #pragma unroll
        for (int r = 0; r < 4; ++r)
          C[(size_t)(m0 + wm + mi * 16 + quad * 4 + r) * HID +
            n0 + wn + ni * 16 + fr] = (bf16)acc[mi][ni][r];
  } else {
    __syncthreads();
    #pragma unroll
    for (int mi = 0; mi < 4; ++mi)
      #pragma unroll
      for (int ni = 0; ni < 4; ++ni)
        #pragma unroll
        for (int r = 0; r < 4; ++r) {
          int row = wn + ni * 16 + fr;
          int col = wm + mi * 16 + quad * 4 + r;
          int colS = (col + 8 * (row & 15)) & 127;
          sbuf[row * 128 + colS] = (bf16)acc[mi][ni][r];
        }
    __syncthreads();
    const int row = t >> 1, cb = (t & 1) * 64;
    #pragma unroll
    for (int j = 0; j < 8; ++j) {
      int c0 = (cb + j * 8 + 8 * (row & 15)) & 127;
      *(bf16x8*)&Vt[(size_t)(n0 + row) * SEQ + m0 + cb + j * 8] =
          *(const bf16x8*)&sbuf[row * 128 + c0];
    }
  }
}

// ---------------------------------------------------------------------------
// O-projection: out = Og[M,K] @ Wto[N,K]^T, fp32 out.
// ---------------------------------------------------------------------------
__global__ __launch_bounds__(256)
void oproj_gemm(const bf16* __restrict__ A, const bf16* __restrict__ Bt,
                float* __restrict__ C)
{
  __shared__ bf16 sbuf[16384];
  bf16* As = sbuf;
  bf16* Bs = sbuf + 8192;

  const int t = threadIdx.x, lane = t & 63, w = t >> 6;
  const int n0 = blockIdx.x * 128, m0 = blockIdx.y * 128;
  const int wm = (w & 1) * 64, wn = (w >> 1) * 64;
  const int fr = lane & 15, quad = lane >> 4;

  f32x4 acc[4][4] = {};

  const int sr = lane >> 3;
  const int sc = ((lane & 7) - sr) & 7;
  const bf16* ga = A  + (size_t)(m0 + w * 32 + sr) * HID + sc * 8;
  const bf16* gb = Bt + (size_t)(n0 + w * 32 + sr) * HID + sc * 8;

  for (int k0 = 0; k0 < HID; k0 += 64) {
    __syncthreads();
    #pragma unroll
    for (int c = 0; c < 4; ++c) {
      gll16(ga + (size_t)(c * 8) * HID + k0, As + (w * 32 + c * 8) * 64);
      gll16(gb + (size_t)(c * 8) * HID + k0, Bs + (w * 32 + c * 8) * 64);
    }
    __syncthreads();
    #pragma unroll
    for (int ks = 0; ks < 2; ++ks) {
      bf16x8 af[4], bg[4];
      #pragma unroll
      for (int i = 0; i < 4; ++i)
        af[i] = *(const bf16x8*)&As[(wm + i * 16 + fr) * 64 +
                                    ((ks * 4 + quad + fr) & 7) * 8];
      #pragma unroll
      for (int i = 0; i < 4; ++i)
        bg[i] = *(const bf16x8*)&Bs[(wn + i * 16 + fr) * 64 +
                                    ((ks * 4 + quad + fr) & 7) * 8];
      #pragma unroll
      for (int mi = 0; mi < 4; ++mi)
        #pragma unroll
        for (int ni = 0; ni < 4; ++ni)
          acc[mi][ni] = __builtin_amdgcn_mfma_f32_16x16x32_bf16(
              af[mi], bg[ni], acc[mi][ni], 0, 0, 0);
    }
  }

  #pragma unroll
  for (int mi = 0; mi < 4; ++mi)
    #pragma unroll
    for (int ni = 0; ni < 4; ++ni)
      #pragma unroll
      for (int r = 0; r < 4; ++r)
        C[(size_t)(m0 + wm + mi * 16 + quad * 4 + r) * HID +
          n0 + wn + ni * 16 + fr] = acc[mi][ni][r];
}

// ---------------------------------------------------------------------------
// Attention v4: KV-split across blockIdx.z (NSPLIT wgs per (q-tile, head)),
// single-buffered 32KB LDS (5 wgs/CU), chunk-rotation swizzle.
// NSPLIT=4: each wg owns one 1024-key block (own local max — exactly the
// reference's per-block semantics), combines via fp32 atomicAdd into
// (numg, deng). NSPLIT=1: all 4 blocks in-kernel, normalize, write Og.
// ---------------------------------------------------------------------------
template <int NSPLIT>
__global__ __launch_bounds__(256)
void attn4(const bf16* __restrict__ Q, const bf16* __restrict__ K,
           const bf16* __restrict__ Vt, float* __restrict__ numg,
           float* __restrict__ deng, bf16* __restrict__ Og)
{
  __shared__ bf16 Ks[4096];
  __shared__ bf16 Vs[4096];
  __shared__ bf16 Ps[4][2048];

  const int t = threadIdx.x, lane = t & 63, w = t >> 6;
  const int h = blockIdx.y, q0 = blockIdx.x * 128;
  const int z = blockIdx.z;
  const int fr = lane & 15, quad = lane >> 4;

  bf16x8 bq[2][2];
  #pragma unroll
  for (int qf = 0; qf < 2; ++qf)
    #pragma unroll
    for (int ks = 0; ks < 2; ++ks)
      bq[qf][ks] = *(const bf16x8*)&Q[(size_t)(q0 + w * 32 + qf * 16 + fr) * HID
                                      + h * 64 + ks * 32 + quad * 8];

  const int sr = lane >> 3;
  const int sc = ((lane & 7) - sr) & 7;
  const int keybase = z * (4 / NSPLIT) * 1024;
  const bf16* gk = K  + (size_t)(keybase + w * 16 + sr) * HID + h * 64 + sc * 8;
  const bf16* gv = Vt + (size_t)(h * 64 + w * 16 + sr) * SEQ + keybase + sc * 8;

  f32x4 accN[2][4] = {};
  f32x4 accO[2][4] = {};
  float m_i[2] = {-3e38f, -3e38f}, l_i[2] = {0.f, 0.f}, dsum[2] = {0.f, 0.f};

  const int NIT = (4 / NSPLIT) * 16;
  for (int kk = 0; kk < NIT; ++kk) {
    __syncthreads();
    {
      const size_t key0 = (size_t)kk * 64;
      #pragma unroll
      for (int j = 0; j < 2; ++j) {
        gll16(gk + (key0 + j * 8) * HID, &Ks[(w * 16 + j * 8) * 64]);
        gll16(gv + key0 + (size_t)(j * 8) * SEQ, &Vs[(w * 16 + j * 8) * 64]);
      }
    }
    __syncthreads();

    bf16x8 ak[4][2];
    #pragma unroll
    for (int mt = 0; mt < 4; ++mt)
      #pragma unroll
      for (int ks = 0; ks < 2; ++ks)
        ak[mt][ks] = *(const bf16x8*)&Ks[(mt * 16 + fr) * 64 +
                                         ((ks * 4 + quad + fr) & 7) * 8];

    #pragma unroll
    for (int qf = 0; qf < 2; ++qf) {
      f32x4 s[4];
      #pragma unroll
      for (int mt = 0; mt < 4; ++mt) {
        f32x4 zz = {};
        zz = __builtin_amdgcn_mfma_f32_16x16x32_bf16(ak[mt][0], bq[qf][0], zz, 0, 0, 0);
        zz = __builtin_amdgcn_mfma_f32_16x16x32_bf16(ak[mt][1], bq[qf][1], zz, 0, 0, 0);
        s[mt] = zz;
      }
      float mx = -3e38f;
      #pragma unroll
      for (int mt = 0; mt < 4; ++mt)
        #pragma unroll
        for (int r = 0; r < 4; ++r) mx = fmaxf(mx, s[mt][r]);
      mx = fmaxf(mx, __shfl_xor(mx, 16));
      mx = fmaxf(mx, __shfl_xor(mx, 32));
      const float mnew = fmaxf(m_i[qf], mx);
      const float alpha = __expf(m_i[qf] - mnew);
      m_i[qf] = mnew;
      float sum = 0.f;
      const int prow = (qf * 16 + fr) * 64;
      #pragma unroll
      for (int mt = 0; mt < 4; ++mt) {
        float p0 = __expf(s[mt][0] - mnew);
        float p1 = __expf(s[mt][1] - mnew);
        float p2 = __expf(s[mt][2] - mnew);
        float p3 = __expf(s[mt][3] - mnew);
        sum += (p0 + p1) + (p2 + p3);
        bf16x4 pv = {(bf16)p0, (bf16)p1, (bf16)p2, (bf16)p3};
        *(bf16x4*)&Ps[w][prow + ((mt * 2 + (quad >> 1) + fr) & 7) * 8 +
                         (quad & 1) * 4] = pv;
      }
      sum += __shfl_xor(sum, 16);
      sum += __shfl_xor(sum, 32);
      l_i[qf] = l_i[qf] * alpha + sum;
      #pragma unroll
      for (int dt = 0; dt < 4; ++dt) accO[qf][dt] *= alpha;
    }

    #pragma unroll
    for (int ks = 0; ks < 2; ++ks) {
      bf16x8 bp0 = *(const bf16x8*)&Ps[w][fr * 64 +
                                          ((ks * 4 + quad + fr) & 7) * 8];
      bf16x8 bp1 = *(const bf16x8*)&Ps[w][(16 + fr) * 64 +
                                          ((ks * 4 + quad + fr) & 7) * 8];
      #pragma unroll
      for (int dt = 0; dt < 4; ++dt) {
        bf16x8 av = *(const bf16x8*)&Vs[(dt * 16 + fr) * 64 +
                                        ((ks * 4 + quad + fr) & 7) * 8];
        accO[0][dt] = __builtin_amdgcn_mfma_f32_16x16x32_bf16(av, bp0, accO[0][dt], 0, 0, 0);
        accO[1][dt] = __builtin_amdgcn_mfma_f32_16x16x32_bf16(av, bp1, accO[1][dt], 0, 0, 0);
      }
    }

    if ((kk & 15) == 15) {   // end of 1024-key block: fold, reset local state
      #pragma unroll
      for (int qf = 0; qf < 2; ++qf) {
        #pragma unroll
        for (int dt = 0; dt < 4; ++dt) {
          #pragma unroll
          for (int r = 0; r < 4; ++r) accN[qf][dt][r] += accO[qf][dt][r];
          accO[qf][dt] = (f32x4){0.f, 0.f, 0.f, 0.f};
        }
        dsum[qf] += l_i[qf];
        l_i[qf] = 0.f;
        m_i[qf] = -3e38f;
      }
    }
  }

  if (NSPLIT == 1) {
    #pragma unroll
    for (int qf = 0; qf < 2; ++qf) {
      const float inv = 1.0f / dsum[qf];
      const size_t orow = (size_t)(q0 + w * 32 + qf * 16 + fr) * HID + h * 64;
      #pragma unroll
      for (int dt = 0; dt < 4; ++dt) {
        bf16x4 ov = {(bf16)(accN[qf][dt][0] * inv), (bf16)(accN[qf][dt][1] * inv),
                     (bf16)(accN[qf][dt][2] * inv), (bf16)(accN[qf][dt][3] * inv)};
        *(bf16x4*)&Og[orow + dt * 16 + quad * 4] = ov;
      }
    }
  } else {
    #pragma unroll
    for (int qf = 0; qf < 2; ++qf) {
      const int qrow = q0 + w * 32 + qf * 16 + fr;
      const size_t orow = (size_t)qrow * HID + h * 64;
      #pragma unroll
      for (int dt = 0; dt < 4; ++dt) {
        #pragma unroll
        for (int r = 0; r < 4; ++r)
          atomicAdd(&numg[orow + dt * 16 + quad * 4 + r], accN[qf][dt][r]);
      }
      if (quad == 0) atomicAdd(&deng[qrow * NHEADS + h], dsum[qf]);
    }
  }
}

// normalize: Og[q][h*64+d] = numg / deng
__global__ __launch_bounds__(256)
void norm_kernel(const float* __restrict__ numg, const float* __restrict__ deng,
                 bf16* __restrict__ Og)
{
  const int gid = blockIdx.x * 256 + threadIdx.x;
  const size_t base = (size_t)gid * 8;
  const int q = (int)(base >> 10), c = (int)(base & 1023), h = c >> 6;
  const float inv = 1.0f / deng[q * NHEADS + h];
  float4 a = *(const float4*)&numg[base];
  float4 b = *(const float4*)&numg[base + 4];
  bf16x8 o = {(bf16)(a.x * inv), (bf16)(a.y * inv), (bf16)(a.z * inv),
              (bf16)(a.w * inv), (bf16)(b.x * inv), (bf16)(b.y * inv),
              (bf16)(b.z * inv), (bf16)(b.w * inv)};
  *(bf16x8*)&Og[base] = o;
}

extern "C" void kernel_launch(void* const* d_in, const int* in_sizes, int n_in,
                              void* d_out, int out_size, void* d_ws, size_t ws_size,
                              hipStream_t stream)
{
  const float* X  = (const float*)d_in[0];
  const float* Wq = (const float*)d_in[1];
  const float* Wk = (const float*)d_in[2];
  const float* Wv = (const float*)d_in[3];
  const float* Wo = (const float*)d_in[4];
  float* out = (float*)d_out;

  const size_t MB = 1024 * 1024;
  bf16*  Xb   = (bf16*)d_ws;                        // 0..8 MB
  bf16*  Wt   = (bf16*)((char*)d_ws + 8  * MB);     // 8..16 MB
  bf16*  Qg   = (bf16*)((char*)d_ws + 16 * MB);     // 16..24 MB
  bf16*  Kg   = (bf16*)((char*)d_ws + 24 * MB);     // 24..32 MB
  bf16*  Vtg  = (bf16*)((char*)d_ws + 32 * MB);     // 32..40 MB
  float* numg = (float*)((char*)d_ws + 40 * MB);    // 40..56 MB (split path)
  float* deng = (float*)((char*)d_ws + 56 * MB);    // 56..56.25 MB
  bf16*  OgS  = (bf16*)((char*)d_ws + 57 * MB);     // 57..65 MB (split path)
  bf16*  OgF  = (bf16*)((char*)d_ws + 40 * MB);     // fallback path

  prep_kernel<<<dim3(256, 1, 5), 256, 0, stream>>>(X, Wq, Wk, Wv, Wo, Xb, Wt);
  qkv_gemm<<<dim3(HID / 128, SEQ / 128, 3), 256, 0, stream>>>(Xb, Wt, Qg, Kg, Vtg);

  const bool split = ws_size >= 68 * MB;
  if (split) {
    hipMemsetAsync((char*)d_ws + 40 * MB, 0,
                   (size_t)SEQ * HID * 4 + (size_t)SEQ * NHEADS * 4, stream);
    attn4<4><<<dim3(SEQ / 128, NHEADS, 4), 256, 0, stream>>>(
        Qg, Kg, Vtg, numg, deng, nullptr);
    norm_kernel<<<(SEQ * HID) / (256 * 8), 256, 0, stream>>>(numg, deng, OgS);
    oproj_gemm<<<dim3(HID / 128, SEQ / 128), 256, 0, stream>>>(
        OgS, Wt + (size_t)3 * HID * HID, out);
  } else {
    attn4<1><<<dim3(SEQ / 128, NHEADS, 1), 256, 0, stream>>>(
        Qg, Kg, Vtg, nullptr, nullptr, OgF);
    oproj_gemm<<<dim3(HID / 128, SEQ / 128), 256, 0, stream>>>(
        OgF, Wt + (size_t)3 * HID * HID, out);
  }
}

// Round 5
// 282.492 us; speedup vs baseline: 1.5158x; 1.5158x over previous
//
#include <hip/hip_runtime.h>
#include <hip/hip_bf16.h>

typedef __bf16 bf16;
typedef bf16 bf16x4 __attribute__((ext_vector_type(4)));
typedef bf16 bf16x8 __attribute__((ext_vector_type(8)));
typedef float f32x4 __attribute__((ext_vector_type(4)));

#define HID 1024
#define NHEADS 16
#define HD 64
#define SEQ 4096

__device__ __forceinline__ void gll16(const void* g, void* l) {
  __builtin_amdgcn_global_load_lds(
      (const __attribute__((address_space(1))) void*)g,
      (__attribute__((address_space(3))) void*)l, 16, 0, 0);
}

// ---------------------------------------------------------------------------
// Prep: z=0 convert X fp32->bf16; z=1..4 transpose+convert W -> Wt[out][in],
// folding attention scale (0.125, exact) into Wq.
// ---------------------------------------------------------------------------
__global__ __launch_bounds__(256)
void prep_kernel(const float* __restrict__ X,
                 const float* __restrict__ Wq, const float* __restrict__ Wk,
                 const float* __restrict__ Wv, const float* __restrict__ Wo,
                 bf16* __restrict__ Xb, bf16* __restrict__ Wt)
{
  const int z = blockIdx.z, t = threadIdx.x, bx = blockIdx.x;
  if (z == 0) {
    const float4* src = (const float4*)X;
    const int gid = bx * 256 + t;
    #pragma unroll
    for (int i = 0; i < 16; ++i) {
      float4 v = src[gid + i * 65536];
      bf16x4 o = {(bf16)v.x, (bf16)v.y, (bf16)v.z, (bf16)v.w};
      *(bf16x4*)&Xb[(size_t)(gid + i * 65536) * 4] = o;
    }
  } else {
    const float* W = (z == 1) ? Wq : (z == 2) ? Wk : (z == 3) ? Wv : Wo;
    bf16* dst = Wt + (size_t)(z - 1) * HID * HID;
    const float scale = (z == 1) ? 0.125f : 1.0f;
    __shared__ bf16 T[64][68];
    const int tr = (bx >> 4) * 64, tc = (bx & 15) * 64;
    #pragma unroll
    for (int p = 0; p < 4; ++p) {
      int row = (t >> 4) + p * 16;
      float4 v = *(const float4*)&W[(size_t)(tr + row) * HID + tc + (t & 15) * 4];
      T[row][(t & 15) * 4 + 0] = (bf16)(v.x * scale);
      T[row][(t & 15) * 4 + 1] = (bf16)(v.y * scale);
      T[row][(t & 15) * 4 + 2] = (bf16)(v.z * scale);
      T[row][(t & 15) * 4 + 3] = (bf16)(v.w * scale);
    }
    __syncthreads();
    #pragma unroll
    for (int p = 0; p < 4; ++p) {
      int rp = (t >> 4) + p * 16;
      int cb = (t & 15) * 4;
      bf16x4 o = {T[cb + 0][rp], T[cb + 1][rp], T[cb + 2][rp], T[cb + 3][rp]};
      *(bf16x4*)&dst[(size_t)(tc + rp) * HID + tr + cb] = o;
    }
  }
}

// ---------------------------------------------------------------------------
// QKV GEMM: C = Xb[M,K] @ Wt[z][N,K]^T. 128x128 tile, BK=64, global_load_lds
// with chunk-rotation swizzle. z=2 writes V transposed (Vt[hid][seq]).
// ---------------------------------------------------------------------------
__global__ __launch_bounds__(256)
void qkv_gemm(const bf16* __restrict__ A, const bf16* __restrict__ Wt,
              bf16* __restrict__ Qg, bf16* __restrict__ Kg,
              bf16* __restrict__ Vt)
{
  __shared__ bf16 sbuf[16384];
  bf16* As = sbuf;
  bf16* Bs = sbuf + 8192;

  const int t = threadIdx.x, lane = t & 63, w = t >> 6;
  const int z = blockIdx.z;
  const int n0 = blockIdx.x * 128, m0 = blockIdx.y * 128;
  const bf16* Bt = Wt + (size_t)z * HID * HID;
  const int wm = (w & 1) * 64, wn = (w >> 1) * 64;
  const int fr = lane & 15, quad = lane >> 4;

  f32x4 acc[4][4] = {};

  const int sr = lane >> 3;
  const int sc = ((lane & 7) - sr) & 7;
  const bf16* ga = A  + (size_t)(m0 + w * 32 + sr) * HID + sc * 8;
  const bf16* gb = Bt + (size_t)(n0 + w * 32 + sr) * HID + sc * 8;

  for (int k0 = 0; k0 < HID; k0 += 64) {
    __syncthreads();
    #pragma unroll
    for (int c = 0; c < 4; ++c) {
      gll16(ga + (size_t)(c * 8) * HID + k0, As + (w * 32 + c * 8) * 64);
      gll16(gb + (size_t)(c * 8) * HID + k0, Bs + (w * 32 + c * 8) * 64);
    }
    __syncthreads();
    #pragma unroll
    for (int ks = 0; ks < 2; ++ks) {
      bf16x8 af[4], bg[4];
      #pragma unroll
      for (int i = 0; i < 4; ++i)
        af[i] = *(const bf16x8*)&As[(wm + i * 16 + fr) * 64 +
                                    ((ks * 4 + quad + fr) & 7) * 8];
      #pragma unroll
      for (int i = 0; i < 4; ++i)
        bg[i] = *(const bf16x8*)&Bs[(wn + i * 16 + fr) * 64 +
                                    ((ks * 4 + quad + fr) & 7) * 8];
      #pragma unroll
      for (int mi = 0; mi < 4; ++mi)
        #pragma unroll
        for (int ni = 0; ni < 4; ++ni)
          acc[mi][ni] = __builtin_amdgcn_mfma_f32_16x16x32_bf16(
              af[mi], bg[ni], acc[mi][ni], 0, 0, 0);
    }
  }

  if (z < 2) {
    bf16* C = z ? Kg : Qg;
    #pragma unroll
    for (int mi = 0; mi < 4; ++mi)
      #pragma unroll
      for (int ni = 0; ni < 4; ++ni)
        #pragma unroll
        for (int r = 0; r < 4; ++r)
          C[(size_t)(m0 + wm + mi * 16 + quad * 4 + r) * HID +
            n0 + wn + ni * 16 + fr] = (bf16)acc[mi][ni][r];
  } else {
    __syncthreads();
    #pragma unroll
    for (int mi = 0; mi < 4; ++mi)
      #pragma unroll
      for (int ni = 0; ni < 4; ++ni)
        #pragma unroll
        for (int r = 0; r < 4; ++r) {
          int row = wn + ni * 16 + fr;
          int col = wm + mi * 16 + quad * 4 + r;
          int colS = (col + 8 * (row & 15)) & 127;
          sbuf[row * 128 + colS] = (bf16)acc[mi][ni][r];
        }
    __syncthreads();
    const int row = t >> 1, cb = (t & 1) * 64;
    #pragma unroll
    for (int j = 0; j < 8; ++j) {
      int c0 = (cb + j * 8 + 8 * (row & 15)) & 127;
      *(bf16x8*)&Vt[(size_t)(n0 + row) * SEQ + m0 + cb + j * 8] =
          *(const bf16x8*)&sbuf[row * 128 + c0];
    }
  }
}

// ---------------------------------------------------------------------------
// O-projection: out = Og[M,K] @ Wto[N,K]^T, fp32 out.
// ---------------------------------------------------------------------------
__global__ __launch_bounds__(256)
void oproj_gemm(const bf16* __restrict__ A, const bf16* __restrict__ Bt,
                float* __restrict__ C)
{
  __shared__ bf16 sbuf[16384];
  bf16* As = sbuf;
  bf16* Bs = sbuf + 8192;

  const int t = threadIdx.x, lane = t & 63, w = t >> 6;
  const int n0 = blockIdx.x * 128, m0 = blockIdx.y * 128;
  const int wm = (w & 1) * 64, wn = (w >> 1) * 64;
  const int fr = lane & 15, quad = lane >> 4;

  f32x4 acc[4][4] = {};

  const int sr = lane >> 3;
  const int sc = ((lane & 7) - sr) & 7;
  const bf16* ga = A  + (size_t)(m0 + w * 32 + sr) * HID + sc * 8;
  const bf16* gb = Bt + (size_t)(n0 + w * 32 + sr) * HID + sc * 8;

  for (int k0 = 0; k0 < HID; k0 += 64) {
    __syncthreads();
    #pragma unroll
    for (int c = 0; c < 4; ++c) {
      gll16(ga + (size_t)(c * 8) * HID + k0, As + (w * 32 + c * 8) * 64);
      gll16(gb + (size_t)(c * 8) * HID + k0, Bs + (w * 32 + c * 8) * 64);
    }
    __syncthreads();
    #pragma unroll
    for (int ks = 0; ks < 2; ++ks) {
      bf16x8 af[4], bg[4];
      #pragma unroll
      for (int i = 0; i < 4; ++i)
        af[i] = *(const bf16x8*)&As[(wm + i * 16 + fr) * 64 +
                                    ((ks * 4 + quad + fr) & 7) * 8];
      #pragma unroll
      for (int i = 0; i < 4; ++i)
        bg[i] = *(const bf16x8*)&Bs[(wn + i * 16 + fr) * 64 +
                                    ((ks * 4 + quad + fr) & 7) * 8];
      #pragma unroll
      for (int mi = 0; mi < 4; ++mi)
        #pragma unroll
        for (int ni = 0; ni < 4; ++ni)
          acc[mi][ni] = __builtin_amdgcn_mfma_f32_16x16x32_bf16(
              af[mi], bg[ni], acc[mi][ni], 0, 0, 0);
    }
  }

  #pragma unroll
  for (int mi = 0; mi < 4; ++mi)
    #pragma unroll
    for (int ni = 0; ni < 4; ++ni)
      #pragma unroll
      for (int r = 0; r < 4; ++r)
        C[(size_t)(m0 + wm + mi * 16 + quad * 4 + r) * HID +
          n0 + wn + ni * 16 + fr] = acc[mi][ni][r];
}

// ---------------------------------------------------------------------------
// Attention v5: 512-thread wgs (8 waves). Waves 0-3 (half 0) process KV
// blocks {0,1}; waves 4-7 (half 1) process blocks {2,3}. Each 1024-key block
// uses its own local max (reference semantics); halves combine (num,den)
// through LDS at the end — no atomics, no extra global traffic.
// Grid 512 wgs x 8 waves = 16 waves/CU (2 wgs/CU co-resident, 66KB LDS).
// ---------------------------------------------------------------------------
__global__ __launch_bounds__(512)
void attn5(const bf16* __restrict__ Q, const bf16* __restrict__ K,
           const bf16* __restrict__ Vt, bf16* __restrict__ Og)
{
  // pool: [0,32K) K/V tiles (2 halves x (K 8K + V 8K));
  //       [32K,64K) Ps 8 waves x 4KB  (aliased as fp32 combine scratch);
  //       [64K,66K) den scratch.
  __shared__ __align__(16) char pool[67584];

  const int t = threadIdx.x, lane = t & 63, w = t >> 6;
  const int half = w >> 2, wl = w & 3;
  const int h = blockIdx.y, q0 = blockIdx.x * 128;
  const int fr = lane & 15, quad = lane >> 4;

  bf16* Kl = (bf16*)pool + half * 8192;
  bf16* Vl = Kl + 4096;
  bf16* Pw = (bf16*)(pool + 32768) + w * 2048;

  bf16x8 bq[2][2];
  #pragma unroll
  for (int qf = 0; qf < 2; ++qf)
    #pragma unroll
    for (int ks = 0; ks < 2; ++ks)
      bq[qf][ks] = *(const bf16x8*)&Q[(size_t)(q0 + wl * 32 + qf * 16 + fr) * HID
                                      + h * 64 + ks * 32 + quad * 8];

  const int sr = lane >> 3;
  const int sc = ((lane & 7) - sr) & 7;
  const int keybase = half * 2048;
  const bf16* gk = K  + (size_t)(keybase + wl * 16 + sr) * HID + h * 64 + sc * 8;
  const bf16* gv = Vt + (size_t)(h * 64 + wl * 16 + sr) * SEQ + keybase + sc * 8;

  f32x4 accN[2][4] = {};
  f32x4 accO[2][4] = {};
  float m_i[2] = {-3e38f, -3e38f}, l_i[2] = {0.f, 0.f}, dsum[2] = {0.f, 0.f};

  for (int kk = 0; kk < 32; ++kk) {
    __syncthreads();
    {
      const size_t key0 = (size_t)kk * 64;
      #pragma unroll
      for (int j = 0; j < 2; ++j) {
        gll16(gk + (key0 + j * 8) * HID, Kl + (wl * 16 + j * 8) * 64);
        gll16(gv + key0 + (size_t)(j * 8) * SEQ, Vl + (wl * 16 + j * 8) * 64);
      }
    }
    __syncthreads();

    bf16x8 ak[4][2];
    #pragma unroll
    for (int mt = 0; mt < 4; ++mt)
      #pragma unroll
      for (int ks = 0; ks < 2; ++ks)
        ak[mt][ks] = *(const bf16x8*)&Kl[(mt * 16 + fr) * 64 +
                                         ((ks * 4 + quad + fr) & 7) * 8];

    #pragma unroll
    for (int qf = 0; qf < 2; ++qf) {
      f32x4 s[4];
      #pragma unroll
      for (int mt = 0; mt < 4; ++mt) {
        f32x4 zz = {};
        zz = __builtin_amdgcn_mfma_f32_16x16x32_bf16(ak[mt][0], bq[qf][0], zz, 0, 0, 0);
        zz = __builtin_amdgcn_mfma_f32_16x16x32_bf16(ak[mt][1], bq[qf][1], zz, 0, 0, 0);
        s[mt] = zz;
      }
      float mx = -3e38f;
      #pragma unroll
      for (int mt = 0; mt < 4; ++mt)
        #pragma unroll
        for (int r = 0; r < 4; ++r) mx = fmaxf(mx, s[mt][r]);
      mx = fmaxf(mx, __shfl_xor(mx, 16));
      mx = fmaxf(mx, __shfl_xor(mx, 32));
      const float mnew = fmaxf(m_i[qf], mx);
      const float alpha = __expf(m_i[qf] - mnew);
      m_i[qf] = mnew;
      float sum = 0.f;
      const int prow = (qf * 16 + fr) * 64;
      #pragma unroll
      for (int mt = 0; mt < 4; ++mt) {
        float p0 = __expf(s[mt][0] - mnew);
        float p1 = __expf(s[mt][1] - mnew);
        float p2 = __expf(s[mt][2] - mnew);
        float p3 = __expf(s[mt][3] - mnew);
        sum += (p0 + p1) + (p2 + p3);
        bf16x4 pv = {(bf16)p0, (bf16)p1, (bf16)p2, (bf16)p3};
        *(bf16x4*)&Pw[prow + ((mt * 2 + (quad >> 1) + fr) & 7) * 8 +
                      (quad & 1) * 4] = pv;
      }
      sum += __shfl_xor(sum, 16);
      sum += __shfl_xor(sum, 32);
      l_i[qf] = l_i[qf] * alpha + sum;
      #pragma unroll
      for (int dt = 0; dt < 4; ++dt) accO[qf][dt] *= alpha;
    }

    #pragma unroll
    for (int ks = 0; ks < 2; ++ks) {
      bf16x8 bp0 = *(const bf16x8*)&Pw[fr * 64 + ((ks * 4 + quad + fr) & 7) * 8];
      bf16x8 bp1 = *(const bf16x8*)&Pw[(16 + fr) * 64 +
                                       ((ks * 4 + quad + fr) & 7) * 8];
      #pragma unroll
      for (int dt = 0; dt < 4; ++dt) {
        bf16x8 av = *(const bf16x8*)&Vl[(dt * 16 + fr) * 64 +
                                        ((ks * 4 + quad + fr) & 7) * 8];
        accO[0][dt] = __builtin_amdgcn_mfma_f32_16x16x32_bf16(av, bp0, accO[0][dt], 0, 0, 0);
        accO[1][dt] = __builtin_amdgcn_mfma_f32_16x16x32_bf16(av, bp1, accO[1][dt], 0, 0, 0);
      }
    }

    if ((kk & 15) == 15) {   // end of a 1024-key block: fold, reset local state
      #pragma unroll
      for (int qf = 0; qf < 2; ++qf) {
        #pragma unroll
        for (int dt = 0; dt < 4; ++dt) {
          #pragma unroll
          for (int r = 0; r < 4; ++r) accN[qf][dt][r] += accO[qf][dt][r];
          accO[qf][dt] = (f32x4){0.f, 0.f, 0.f, 0.f};
        }
        dsum[qf] += l_i[qf];
        l_i[qf] = 0.f;
        m_i[qf] = -3e38f;
      }
    }
  }

  // -------- combine halves through LDS (element-major: conflict-free) -----
  __syncthreads();                       // all Ps/KV reads done; safe to alias
  float* scr = (float*)(pool + 32768);   // 32 elems x 256 lanes = 32KB
  float* dS  = (float*)(pool + 65536);   // 128 q-rows x ... (256 slots used)
  if (half == 1) {
    #pragma unroll
    for (int qf = 0; qf < 2; ++qf) {
      #pragma unroll
      for (int dt = 0; dt < 4; ++dt)
        #pragma unroll
        for (int r = 0; r < 4; ++r)
          scr[(qf * 16 + dt * 4 + r) * 256 + wl * 64 + lane] = accN[qf][dt][r];
      if (quad == 0) dS[wl * 32 + qf * 16 + fr] = dsum[qf];
    }
  }
  __syncthreads();
  if (half == 0) {
    #pragma unroll
    for (int qf = 0; qf < 2; ++qf) {
      const float dtot = dsum[qf] + dS[wl * 32 + qf * 16 + fr];
      const float inv = 1.0f / dtot;
      const size_t orow = (size_t)(q0 + wl * 32 + qf * 16 + fr) * HID + h * 64;
      #pragma unroll
      for (int dt = 0; dt < 4; ++dt) {
        float v0 = accN[qf][dt][0] + scr[(qf * 16 + dt * 4 + 0) * 256 + wl * 64 + lane];
        float v1 = accN[qf][dt][1] + scr[(qf * 16 + dt * 4 + 1) * 256 + wl * 64 + lane];
        float v2 = accN[qf][dt][2] + scr[(qf * 16 + dt * 4 + 2) * 256 + wl * 64 + lane];
        float v3 = accN[qf][dt][3] + scr[(qf * 16 + dt * 4 + 3) * 256 + wl * 64 + lane];
        bf16x4 ov = {(bf16)(v0 * inv), (bf16)(v1 * inv),
                     (bf16)(v2 * inv), (bf16)(v3 * inv)};
        *(bf16x4*)&Og[orow + dt * 16 + quad * 4] = ov;
      }
    }
  }
}

extern "C" void kernel_launch(void* const* d_in, const int* in_sizes, int n_in,
                              void* d_out, int out_size, void* d_ws, size_t ws_size,
                              hipStream_t stream)
{
  const float* X  = (const float*)d_in[0];
  const float* Wq = (const float*)d_in[1];
  const float* Wk = (const float*)d_in[2];
  const float* Wv = (const float*)d_in[3];
  const float* Wo = (const float*)d_in[4];
  float* out = (float*)d_out;

  const size_t MB = 1024 * 1024;
  bf16* Xb  = (bf16*)d_ws;                       // 0..8 MB (dead after qkv)
  bf16* Wt  = (bf16*)((char*)d_ws + 8  * MB);    // 8..16 MB
  bf16* Qg  = (bf16*)((char*)d_ws + 16 * MB);    // 16..24 MB
  bf16* Kg  = (bf16*)((char*)d_ws + 24 * MB);    // 24..32 MB
  bf16* Vtg = (bf16*)((char*)d_ws + 32 * MB);    // 32..40 MB
  bf16* Og  = (bf16*)d_ws;                       // reuse Xb region

  prep_kernel<<<dim3(256, 1, 5), 256, 0, stream>>>(X, Wq, Wk, Wv, Wo, Xb, Wt);
  qkv_gemm<<<dim3(HID / 128, SEQ / 128, 3), 256, 0, stream>>>(Xb, Wt, Qg, Kg, Vtg);
  attn5<<<dim3(SEQ / 128, NHEADS), 512, 0, stream>>>(Qg, Kg, Vtg, Og);
  oproj_gemm<<<dim3(HID / 128, SEQ / 128), 256, 0, stream>>>(
      Og, Wt + (size_t)3 * HID * HID, out);
}